// Round 4
// baseline (304.264 us; speedup 1.0000x reference)
//
#include <hip/hip_runtime.h>
#include <stdint.h>
#include <stddef.h>

#define B_ 4
#define S_ 2048
#define D_ 256
#define H_ 4
#define DH_ 64
#define NT 128
#define SC_LOG2E 0.18033688011112042f  // (1/8) * log2(e)

typedef __attribute__((ext_vector_type(8))) short short8;
typedef __attribute__((ext_vector_type(4))) short short4v;
typedef __attribute__((ext_vector_type(4))) float f32x4;
typedef unsigned int uint;

__device__ __forceinline__ short bf16_rne(float f) {
  union { float f; uint32_t u; } c; c.f = f;
  uint32_t u = c.u + 0x7FFFu + ((c.u >> 16) & 1u);
  return (short)(u >> 16);
}

__device__ __forceinline__ f32x4 mfma16(short8 a, short8 b, f32x4 c) {
  return __builtin_amdgcn_mfma_f32_16x16x32_bf16(a, b, c, 0, 0, 0);
}

// ---------------- weight prep: transpose+cast to bf16 ----------------
__global__ void prep_weights(const float* __restrict__ Wq, const float* __restrict__ Wk,
                             const float* __restrict__ Wv,
                             short* __restrict__ WqT, short* __restrict__ WkT,
                             short* __restrict__ WvT) {
  int tid = blockIdx.x * blockDim.x + threadIdx.x;
  if (tid < 65536) {
    int n = tid >> 8, d = tid & 255;
    int hh = n >> 6, e = n & 63;
    WqT[tid] = bf16_rne(Wq[((size_t)hh * D_ + d) * DH_ + e]);
    WkT[tid] = bf16_rne(Wk[((size_t)hh * D_ + d) * DH_ + e]);
  } else if (tid < 65536 + 16384) {
    int t2 = tid - 65536;
    int e = t2 >> 8, d = t2 & 255;
    WvT[t2] = bf16_rne(Wv[(size_t)d * DH_ + e]);
  }
}

// ---------------- mask dtype detect: 1 = int32, 0 = byte/bool ----------------
__global__ void detect_kernel(const unsigned int* __restrict__ m, int* __restrict__ flag) {
  __shared__ int isbool;
  if (threadIdx.x == 0) isbool = 0;
  __syncthreads();
#pragma unroll
  for (int i = 0; i < 4; ++i) {
    unsigned int d = m[threadIdx.x + i * 256];
    if (d & 0xFFFFFFFEu) isbool = 1;
  }
  __syncthreads();
  if (threadIdx.x == 0) *flag = isbool ? 0 : 1;
}

// ---------------- bit-pack mask: [B,S,S] -> [B,S,S/32] dwords ----------------
__global__ __launch_bounds__(256) void pack_mask(const unsigned char* __restrict__ maskB,
                                                 const int* __restrict__ flagp,
                                                 uint* __restrict__ mbits) {
  int tid = blockIdx.x * 256 + threadIdx.x;  // 524288 dwords total
  uint w = 0;
  if (*flagp) {  // int32 mask
    const uint4* p = (const uint4*)((const uint*)maskB + (size_t)tid * 32);
#pragma unroll
    for (int i = 0; i < 8; ++i) {
      uint4 d = p[i];
      w |= (d.x ? 1u : 0u) << (i * 4);
      w |= (d.y ? 1u : 0u) << (i * 4 + 1);
      w |= (d.z ? 1u : 0u) << (i * 4 + 2);
      w |= (d.w ? 1u : 0u) << (i * 4 + 3);
    }
  } else {  // byte mask
    const uint4* p = (const uint4*)(maskB + (size_t)tid * 32);
#pragma unroll
    for (int i = 0; i < 2; ++i) {
      uint4 d = p[i];
      const uint* dw = (const uint*)&d;
#pragma unroll
      for (int j = 0; j < 4; ++j) {
        uint x = dw[j];
        int base = i * 16 + j * 4;
        w |= ((x & 0x000000FFu) ? 1u : 0u) << (base);
        w |= ((x & 0x0000FF00u) ? 1u : 0u) << (base + 1);
        w |= ((x & 0x00FF0000u) ? 1u : 0u) << (base + 2);
        w |= ((x & 0xFF000000u) ? 1u : 0u) << (base + 3);
      }
    }
  }
  mbits[tid] = w;
}

// ---------------- projections ----------------
__global__ __launch_bounds__(256) void proj_kernel(
    const float* __restrict__ X, const short* __restrict__ WT,
    const float* __restrict__ bias, short* __restrict__ outp, int vmode) {
  const int b = blockIdx.z;
  const int s0 = blockIdx.x * 64;
  const int n0 = blockIdx.y * 64;
  const int tid = threadIdx.x;
  const int wave = tid >> 6, lane = tid & 63;
  const int lr = lane & 15, lg = lane >> 4;

  const int arowi = s0 + wave * 16 + lr;
  const float* xr = X + ((size_t)b * S_ + arowi) * D_;

  f32x4 zero4 = {0.f, 0.f, 0.f, 0.f};
  f32x4 acc[4];
#pragma unroll
  for (int ct = 0; ct < 4; ++ct) acc[ct] = zero4;

#pragma unroll
  for (int c = 0; c < 8; ++c) {
    const int k0 = c * 32 + lg * 8;
    f32x4 x0 = *(const f32x4*)(xr + k0);
    f32x4 x1 = *(const f32x4*)(xr + k0 + 4);
    short8 a;
#pragma unroll
    for (int jj = 0; jj < 4; ++jj) { a[jj] = bf16_rne(x0[jj]); a[4 + jj] = bf16_rne(x1[jj]); }
#pragma unroll
    for (int ct = 0; ct < 4; ++ct) {
      short8 bw = *(const short8*)(WT + (size_t)(n0 + ct * 16 + lr) * D_ + k0);
      acc[ct] = mfma16(a, bw, acc[ct]);
    }
  }

  if (vmode == 0) {
#pragma unroll
    for (int ct = 0; ct < 4; ++ct) {
      int n = n0 + ct * 16 + lr;
      float bb = bias[n];
      int hh = n >> 6, e = n & 63;
#pragma unroll
      for (int r = 0; r < 4; ++r) {
        int srow = s0 + wave * 16 + lg * 4 + r;
        outp[(((size_t)b * H_ + hh) * S_ + srow) * DH_ + e] = bf16_rne(acc[ct][r] + bb);
      }
    }
  } else {
#pragma unroll
    for (int ct = 0; ct < 4; ++ct) {
      int n = n0 + ct * 16 + lr;
      float bb = bias[n];
      int s4 = s0 + wave * 16 + lg * 4;
      short4v pk;
#pragma unroll
      for (int r = 0; r < 4; ++r) pk[r] = bf16_rne(acc[ct][r] + bb);
      *(short4v*)(outp + ((size_t)b * DH_ + n) * S_ + s4) = pk;
    }
  }
}

// ---------------- fused masked attention (t-split, 4 waves, 32 waves/CU) ----------------
// grid (128, H, B), 256 thr. Each wave: 16 q-rows (q0..q0+15) x t-quarter [w*512, w*512+512).
// Lane layout (swapped MFMA): q = lr, t = lg*4+r. K,V direct from global (L2-resident).
__global__ __launch_bounds__(256, 6) void attn_kernel(
    const short* __restrict__ qh, const short* __restrict__ kh,
    const short* __restrict__ vT, const uint* __restrict__ mbits,
    float* __restrict__ attn, float* __restrict__ heads) {
  __shared__ __align__(16) short Pt[4][16][NT];  // 16 KB (per-wave P, swizzled); aliased as ocomb
  __shared__ float fsum[4][16];

  const int b = blockIdx.z, h = blockIdx.y;
  const int q0 = blockIdx.x * 16;
  const int tid = threadIdx.x;
  const int wave = tid >> 6, lane = tid & 63;
  const int lr = lane & 15, lg = lane >> 4;

  const size_t bh = (size_t)b * H_ + h;
  const short* Qb = qh + bh * S_ * DH_;
  const short* Kb = kh + bh * S_ * DH_;
  const short* Vb = vT + (size_t)b * DH_ * S_;

  const int qrow = q0 + lr;
  const uint* mrow = mbits + ((size_t)b * S_ + qrow) * (S_ / 32);
  float* arow = attn + (bh * S_ + qrow) * S_;

  const short8 aq0 = *(const short8*)(Qb + (size_t)qrow * DH_ + lg * 8);
  const short8 aq1 = *(const short8*)(Qb + (size_t)qrow * DH_ + 32 + lg * 8);

  short* pw = &Pt[wave][0][0];
  const int tw0 = wave * 512;  // this wave's t-range start

  // -------- phase 1: partial row sums over this wave's t-quarter --------
  float rsum = 0.f;
  for (int t0 = tw0; t0 < tw0 + 512; t0 += NT) {
    uint4 mv = *(const uint4*)(mrow + (t0 >> 5));
#pragma unroll
    for (int j = 0; j < 8; ++j) {
      const short* kr = Kb + (size_t)(t0 + j * 16 + lr) * DH_ + lg * 8;
      short8 bk0 = *(const short8*)(kr);
      short8 bk1 = *(const short8*)(kr + 32);
      f32x4 acc = {0.f, 0.f, 0.f, 0.f};
      acc = mfma16(bk0, aq0, acc);
      acc = mfma16(bk1, aq1, acc);
      uint mw = ((const uint*)&mv)[j >> 1];
#pragma unroll
      for (int r = 0; r < 4; ++r) {
        int sh = (j & 1) * 16 + lg * 4 + r;
        float p = ((mw >> sh) & 1u) ? 0.f : __builtin_exp2f(acc[r] * SC_LOG2E);
        rsum += p;
      }
    }
  }
  rsum += __shfl_xor(rsum, 16);
  rsum += __shfl_xor(rsum, 32);
  if (lane < 16) fsum[wave][lr] = rsum;
  __syncthreads();
  const float rinv = 1.0f / (fsum[0][lr] + fsum[1][lr] + fsum[2][lr] + fsum[3][lr]);

  // -------- phase 2: recompute, write attn (float4), PV partials --------
  f32x4 o[4];
#pragma unroll
  for (int ct = 0; ct < 4; ++ct) o[ct] = (f32x4){0.f, 0.f, 0.f, 0.f};

  for (int t0 = tw0; t0 < tw0 + 512; t0 += NT) {
    uint4 mv = *(const uint4*)(mrow + (t0 >> 5));
#pragma unroll
    for (int j = 0; j < 8; ++j) {
      const short* kr = Kb + (size_t)(t0 + j * 16 + lr) * DH_ + lg * 8;
      short8 bk0 = *(const short8*)(kr);
      short8 bk1 = *(const short8*)(kr + 32);
      f32x4 acc = {0.f, 0.f, 0.f, 0.f};
      acc = mfma16(bk0, aq0, acc);
      acc = mfma16(bk1, aq1, acc);
      uint mw = ((const uint*)&mv)[j >> 1];
      f32x4 pst;
      short4v pk;
#pragma unroll
      for (int r = 0; r < 4; ++r) {
        int sh = (j & 1) * 16 + lg * 4 + r;
        float p = ((mw >> sh) & 1u) ? 0.f : __builtin_exp2f(acc[r] * SC_LOG2E) * rinv;
        pst[r] = p;
        pk[r] = bf16_rne(p);
      }
      *(f32x4*)(arow + t0 + j * 16 + lg * 4) = pst;
      int slot = j * 2 + (lg >> 1);
      *(short4v*)(pw + lr * 128 + ((slot ^ lr) * 8) + (lg & 1) * 4) = pk;
    }
    // PV: o[e][q] += V^T[e][t] * P[q][t]  (V direct from global/L2)
#pragma unroll
    for (int ct = 0; ct < 4; ++ct) {
#pragma unroll
      for (int kc = 0; kc < 4; ++kc) {
        short8 apf = *(const short8*)(pw + lr * 128 + (((kc * 4 + lg) ^ lr) * 8));
        short8 bvf = *(const short8*)(Vb + (size_t)(ct * 16 + lr) * S_ + t0 + kc * 32 + lg * 8);
        o[ct] = mfma16(bvf, apf, o[ct]);
      }
    }
  }

  // -------- combine o partials across the 4 waves (reuse Pt as float buffer) --------
  __syncthreads();  // all waves done with their Pt slabs
  float* ocomb = (float*)&Pt[0][0][0];  // [4][16][64] floats = 16 KB
#pragma unroll
  for (int ct = 0; ct < 4; ++ct)
    *(f32x4*)(ocomb + wave * 1024 + lr * 64 + ct * 16 + lg * 4) = o[ct];
  __syncthreads();
  {
    int qi = tid >> 4, ec = (tid & 15) * 4;
    f32x4 s = *(const f32x4*)(ocomb + qi * 64 + ec);
#pragma unroll
    for (int w = 1; w < 4; ++w) {
      f32x4 t = *(const f32x4*)(ocomb + w * 1024 + qi * 64 + ec);
      s[0] += t[0]; s[1] += t[1]; s[2] += t[2]; s[3] += t[3];
    }
    *(f32x4*)(heads + (bh * S_ + q0 + qi) * DH_ + ec) = s;
  }
}

// ---------------- mean over heads + final projection ----------------
__global__ __launch_bounds__(256) void final_kernel(
    const float* __restrict__ heads, const float* __restrict__ Wf,
    float* __restrict__ outp) {
  __shared__ float mean[16][DH_];
  const int row0 = blockIdx.x * 16;
  const int tid = threadIdx.x;
#pragma unroll
  for (int i = 0; i < 4; ++i) {
    int idx = tid + i * 256;
    int r = idx >> 6, e = idx & 63;
    int gs = row0 + r;
    int bb = gs >> 11, ss = gs & (S_ - 1);
    float acc = 0.f;
#pragma unroll
    for (int hh = 0; hh < H_; ++hh)
      acc += heads[(((size_t)bb * H_ + hh) * S_ + ss) * DH_ + e];
    mean[r][e] = acc * 0.25f;
  }
  __syncthreads();
  float acc[16];
#pragma unroll
  for (int r = 0; r < 16; ++r) acc[r] = 0.f;
  for (int e = 0; e < DH_; ++e) {
    float wf = Wf[(size_t)e * D_ + tid];
#pragma unroll
    for (int r = 0; r < 16; ++r) acc[r] += mean[r][e] * wf;
  }
#pragma unroll
  for (int r = 0; r < 16; ++r)
    outp[(size_t)(row0 + r) * D_ + tid] = acc[r];
}

extern "C" void kernel_launch(void* const* d_in, const int* in_sizes, int n_in,
                              void* d_out, int out_size, void* d_ws, size_t ws_size,
                              hipStream_t stream) {
  (void)in_sizes; (void)n_in; (void)out_size; (void)ws_size;
  const float* q  = (const float*)d_in[0];
  const float* k  = (const float*)d_in[1];
  const float* v  = (const float*)d_in[2];
  const unsigned char* mask = (const unsigned char*)d_in[3];
  const float* Wq = (const float*)d_in[4];
  const float* bq = (const float*)d_in[5];
  const float* Wk = (const float*)d_in[6];
  const float* bk = (const float*)d_in[7];
  const float* Wv = (const float*)d_in[8];
  const float* bv = (const float*)d_in[9];
  const float* Wf = (const float*)d_in[10];

  float* out  = (float*)d_out;
  float* attn = out + (size_t)B_ * S_ * D_;

  char* ws = (char*)d_ws;
  short* qh    = (short*)(ws);
  short* kh    = (short*)(ws + 4194304);
  short* vT    = (short*)(ws + 8388608);
  short* WqT   = (short*)(ws + 9437184);
  short* WkT   = (short*)(ws + 9568256);
  short* WvT   = (short*)(ws + 9699328);
  float* heads = (float*)(ws + 9732096);
  int*   flag  = (int*)(ws + 18120704);
  uint*  mbits = (uint*)(ws + 18120768);  // 2 MB bit-packed mask

  detect_kernel<<<1, 256, 0, stream>>>((const unsigned int*)mask, flag);
  pack_mask<<<2048, 256, 0, stream>>>(mask, flag, mbits);
  prep_weights<<<320, 256, 0, stream>>>(Wq, Wk, Wv, WqT, WkT, WvT);
  proj_kernel<<<dim3(32, 4, B_), 256, 0, stream>>>(q, WqT, bq, qh, 0);
  proj_kernel<<<dim3(32, 4, B_), 256, 0, stream>>>(k, WkT, bk, kh, 0);
  proj_kernel<<<dim3(32, 1, B_), 256, 0, stream>>>(v, WvT, bv, vT, 1);
  attn_kernel<<<dim3(128, H_, B_), 256, 0, stream>>>(qh, kh, vT, mbits, attn, heads);
  final_kernel<<<512, 256, 0, stream>>>(heads, Wf, out);
}

// Round 5
// 279.346 us; speedup vs baseline: 1.0892x; 1.0892x over previous
//
#include <hip/hip_runtime.h>
#include <stdint.h>
#include <stddef.h>

#define B_ 4
#define S_ 2048
#define D_ 256
#define H_ 4
#define DH_ 64
#define NT 128
#define SC_LOG2E 0.18033688011112042f  // (1/8) * log2(e)

typedef __attribute__((ext_vector_type(8))) short short8;
typedef __attribute__((ext_vector_type(4))) short short4v;
typedef __attribute__((ext_vector_type(4))) float f32x4;
typedef unsigned int uint;

__device__ __forceinline__ short bf16_rne(float f) {
  union { float f; uint32_t u; } c; c.f = f;
  uint32_t u = c.u + 0x7FFFu + ((c.u >> 16) & 1u);
  return (short)(u >> 16);
}

__device__ __forceinline__ f32x4 mfma16(short8 a, short8 b, f32x4 c) {
  return __builtin_amdgcn_mfma_f32_16x16x32_bf16(a, b, c, 0, 0, 0);
}

// ---------------- weight prep: transpose+cast to bf16 ----------------
__global__ void prep_weights(const float* __restrict__ Wq, const float* __restrict__ Wk,
                             const float* __restrict__ Wv,
                             short* __restrict__ WqT, short* __restrict__ WkT,
                             short* __restrict__ WvT) {
  int tid = blockIdx.x * blockDim.x + threadIdx.x;
  if (tid < 65536) {
    int n = tid >> 8, d = tid & 255;
    int hh = n >> 6, e = n & 63;
    WqT[tid] = bf16_rne(Wq[((size_t)hh * D_ + d) * DH_ + e]);
    WkT[tid] = bf16_rne(Wk[((size_t)hh * D_ + d) * DH_ + e]);
  } else if (tid < 65536 + 16384) {
    int t2 = tid - 65536;
    int e = t2 >> 8, d = t2 & 255;
    WvT[t2] = bf16_rne(Wv[(size_t)d * DH_ + e]);
  }
}

// ---------------- mask dtype detect: 1 = int32, 0 = byte/bool ----------------
__global__ void detect_kernel(const unsigned int* __restrict__ m, int* __restrict__ flag) {
  __shared__ int isbool;
  if (threadIdx.x == 0) isbool = 0;
  __syncthreads();
#pragma unroll
  for (int i = 0; i < 4; ++i) {
    unsigned int d = m[threadIdx.x + i * 256];
    if (d & 0xFFFFFFFEu) isbool = 1;
  }
  __syncthreads();
  if (threadIdx.x == 0) *flag = isbool ? 0 : 1;
}

// ---------------- bit-pack mask: [B,S,S] -> [B,S,S/32] dwords ----------------
__global__ __launch_bounds__(256) void pack_mask(const unsigned char* __restrict__ maskB,
                                                 const int* __restrict__ flagp,
                                                 uint* __restrict__ mbits) {
  int tid = blockIdx.x * 256 + threadIdx.x;  // 524288 dwords total
  uint w = 0;
  if (*flagp) {  // int32 mask
    const uint4* p = (const uint4*)((const uint*)maskB + (size_t)tid * 32);
#pragma unroll
    for (int i = 0; i < 8; ++i) {
      uint4 d = p[i];
      w |= (d.x ? 1u : 0u) << (i * 4);
      w |= (d.y ? 1u : 0u) << (i * 4 + 1);
      w |= (d.z ? 1u : 0u) << (i * 4 + 2);
      w |= (d.w ? 1u : 0u) << (i * 4 + 3);
    }
  } else {  // byte mask
    const uint4* p = (const uint4*)(maskB + (size_t)tid * 32);
#pragma unroll
    for (int i = 0; i < 2; ++i) {
      uint4 d = p[i];
      const uint* dw = (const uint*)&d;
#pragma unroll
      for (int j = 0; j < 4; ++j) {
        uint x = dw[j];
        int base = i * 16 + j * 4;
        w |= ((x & 0x000000FFu) ? 1u : 0u) << (base);
        w |= ((x & 0x0000FF00u) ? 1u : 0u) << (base + 1);
        w |= ((x & 0x00FF0000u) ? 1u : 0u) << (base + 2);
        w |= ((x & 0xFF000000u) ? 1u : 0u) << (base + 3);
      }
    }
  }
  mbits[tid] = w;
}

// ---------------- projections ----------------
__global__ __launch_bounds__(256) void proj_kernel(
    const float* __restrict__ X, const short* __restrict__ WT,
    const float* __restrict__ bias, short* __restrict__ outp, int vmode) {
  const int b = blockIdx.z;
  const int s0 = blockIdx.x * 64;
  const int n0 = blockIdx.y * 64;
  const int tid = threadIdx.x;
  const int wave = tid >> 6, lane = tid & 63;
  const int lr = lane & 15, lg = lane >> 4;

  const int arowi = s0 + wave * 16 + lr;
  const float* xr = X + ((size_t)b * S_ + arowi) * D_;

  f32x4 zero4 = {0.f, 0.f, 0.f, 0.f};
  f32x4 acc[4];
#pragma unroll
  for (int ct = 0; ct < 4; ++ct) acc[ct] = zero4;

#pragma unroll
  for (int c = 0; c < 8; ++c) {
    const int k0 = c * 32 + lg * 8;
    f32x4 x0 = *(const f32x4*)(xr + k0);
    f32x4 x1 = *(const f32x4*)(xr + k0 + 4);
    short8 a;
#pragma unroll
    for (int jj = 0; jj < 4; ++jj) { a[jj] = bf16_rne(x0[jj]); a[4 + jj] = bf16_rne(x1[jj]); }
#pragma unroll
    for (int ct = 0; ct < 4; ++ct) {
      short8 bw = *(const short8*)(WT + (size_t)(n0 + ct * 16 + lr) * D_ + k0);
      acc[ct] = mfma16(a, bw, acc[ct]);
    }
  }

  if (vmode == 0) {
#pragma unroll
    for (int ct = 0; ct < 4; ++ct) {
      int n = n0 + ct * 16 + lr;
      float bb = bias[n];
      int hh = n >> 6, e = n & 63;
#pragma unroll
      for (int r = 0; r < 4; ++r) {
        int srow = s0 + wave * 16 + lg * 4 + r;
        outp[(((size_t)b * H_ + hh) * S_ + srow) * DH_ + e] = bf16_rne(acc[ct][r] + bb);
      }
    }
  } else {
#pragma unroll
    for (int ct = 0; ct < 4; ++ct) {
      int n = n0 + ct * 16 + lr;
      float bb = bias[n];
      int s4 = s0 + wave * 16 + lg * 4;
      short4v pk;
#pragma unroll
      for (int r = 0; r < 4; ++r) pk[r] = bf16_rne(acc[ct][r] + bb);
      *(short4v*)(outp + ((size_t)b * DH_ + n) * S_ + s4) = pk;
    }
  }
}

// ---------------- fused masked attention (independent waves, reg-staged tiles) ----------------
// grid (32, H, B), 256 thr. Wave w owns q-rows [q0+w*16, q0+w*16+16); all waves scan the
// SAME t-window together (L1/L2 reuse). Zero barriers. Per tile: bulk-issue all K (and V)
// loads into registers, then compute — HBM/L2 latency amortized once per tile, not per j.
// Lane layout (swapped MFMA): q = lr, t = lg*4+r.
__global__ __launch_bounds__(256) void attn_kernel(
    const short* __restrict__ qh, const short* __restrict__ kh,
    const short* __restrict__ vT, const uint* __restrict__ mbits,
    float* __restrict__ attn, float* __restrict__ heads) {
  __shared__ __align__(16) short Pt[4][16][NT];  // 16 KB; 4 KB private slab per wave

  const int b = blockIdx.z, h = blockIdx.y;
  const int tid = threadIdx.x;
  const int wave = tid >> 6, lane = tid & 63;
  const int lr = lane & 15, lg = lane >> 4;
  const int q0 = blockIdx.x * 64 + wave * 16;

  const size_t bh = (size_t)b * H_ + h;
  const short* Qb = qh + bh * S_ * DH_;
  const short* Kb = kh + bh * S_ * DH_;
  const short* Vb = vT + (size_t)b * DH_ * S_;

  const int qrow = q0 + lr;
  const uint* mrow = mbits + ((size_t)b * S_ + qrow) * (S_ / 32);
  float* arow = attn + (bh * S_ + qrow) * S_;

  const short8 aq0 = *(const short8*)(Qb + (size_t)qrow * DH_ + lg * 8);
  const short8 aq1 = *(const short8*)(Qb + (size_t)qrow * DH_ + 32 + lg * 8);

  short* pw = &Pt[wave][0][0];

  // -------- pass 1: row sums (bulk K reg-staging per tile) --------
  float rsum = 0.f;
  for (int t0 = 0; t0 < S_; t0 += NT) {
    short8 kf[8][2];
#pragma unroll
    for (int j = 0; j < 8; ++j) {
      const short* kr = Kb + (size_t)(t0 + j * 16 + lr) * DH_ + lg * 8;
      kf[j][0] = *(const short8*)(kr);
      kf[j][1] = *(const short8*)(kr + 32);
    }
    uint4 mv = *(const uint4*)(mrow + (t0 >> 5));
#pragma unroll
    for (int j = 0; j < 8; ++j) {
      f32x4 acc = {0.f, 0.f, 0.f, 0.f};
      acc = mfma16(kf[j][0], aq0, acc);
      acc = mfma16(kf[j][1], aq1, acc);
      uint mw = ((const uint*)&mv)[j >> 1];
#pragma unroll
      for (int r = 0; r < 4; ++r) {
        int sh = (j & 1) * 16 + lg * 4 + r;
        float p = ((mw >> sh) & 1u) ? 0.f : __builtin_exp2f(acc[r] * SC_LOG2E);
        rsum += p;
      }
    }
  }
  rsum += __shfl_xor(rsum, 16);
  rsum += __shfl_xor(rsum, 32);
  const float rinv = 1.0f / rsum;

  // -------- pass 2: recompute, write attn (float4), PV --------
  f32x4 o[4];
#pragma unroll
  for (int ct = 0; ct < 4; ++ct) o[ct] = (f32x4){0.f, 0.f, 0.f, 0.f};

  for (int t0 = 0; t0 < S_; t0 += NT) {
    short8 kf[8][2];
#pragma unroll
    for (int j = 0; j < 8; ++j) {
      const short* kr = Kb + (size_t)(t0 + j * 16 + lr) * DH_ + lg * 8;
      kf[j][0] = *(const short8*)(kr);
      kf[j][1] = *(const short8*)(kr + 32);
    }
    short8 vf[4][4];
#pragma unroll
    for (int ct = 0; ct < 4; ++ct)
#pragma unroll
      for (int kc = 0; kc < 4; ++kc)
        vf[ct][kc] = *(const short8*)(Vb + (size_t)(ct * 16 + lr) * S_ + t0 + kc * 32 + lg * 8);

    uint4 mv = *(const uint4*)(mrow + (t0 >> 5));
#pragma unroll
    for (int j = 0; j < 8; ++j) {
      f32x4 acc = {0.f, 0.f, 0.f, 0.f};
      acc = mfma16(kf[j][0], aq0, acc);
      acc = mfma16(kf[j][1], aq1, acc);
      uint mw = ((const uint*)&mv)[j >> 1];
      f32x4 pst;
      short4v pk;
#pragma unroll
      for (int r = 0; r < 4; ++r) {
        int sh = (j & 1) * 16 + lg * 4 + r;
        float p = ((mw >> sh) & 1u) ? 0.f : __builtin_exp2f(acc[r] * SC_LOG2E) * rinv;
        pst[r] = p;
        pk[r] = bf16_rne(p);
      }
      *(f32x4*)(arow + t0 + j * 16 + lg * 4) = pst;
      int slot = j * 2 + (lg >> 1);
      *(short4v*)(pw + lr * 128 + ((slot ^ lr) * 8) + (lg & 1) * 4) = pk;
    }
    // PV: o[e][q] += V^T[e][t] * P[q][t]
#pragma unroll
    for (int ct = 0; ct < 4; ++ct) {
#pragma unroll
      for (int kc = 0; kc < 4; ++kc) {
        short8 apf = *(const short8*)(pw + lr * 128 + (((kc * 4 + lg) ^ lr) * 8));
        o[ct] = mfma16(vf[ct][kc], apf, o[ct]);
      }
    }
  }

#pragma unroll
  for (int ct = 0; ct < 4; ++ct)
    *(f32x4*)(heads + (bh * S_ + qrow) * DH_ + ct * 16 + lg * 4) = o[ct];
}

// ---------------- mean over heads + final projection ----------------
__global__ __launch_bounds__(256) void final_kernel(
    const float* __restrict__ heads, const float* __restrict__ Wf,
    float* __restrict__ outp) {
  __shared__ float mean[16][DH_];
  const int row0 = blockIdx.x * 16;
  const int tid = threadIdx.x;
#pragma unroll
  for (int i = 0; i < 4; ++i) {
    int idx = tid + i * 256;
    int r = idx >> 6, e = idx & 63;
    int gs = row0 + r;
    int bb = gs >> 11, ss = gs & (S_ - 1);
    float acc = 0.f;
#pragma unroll
    for (int hh = 0; hh < H_; ++hh)
      acc += heads[(((size_t)bb * H_ + hh) * S_ + ss) * DH_ + e];
    mean[r][e] = acc * 0.25f;
  }
  __syncthreads();
  float acc[16];
#pragma unroll
  for (int r = 0; r < 16; ++r) acc[r] = 0.f;
  for (int e = 0; e < DH_; ++e) {
    float wf = Wf[(size_t)e * D_ + tid];
#pragma unroll
    for (int r = 0; r < 16; ++r) acc[r] += mean[r][e] * wf;
  }
#pragma unroll
  for (int r = 0; r < 16; ++r)
    outp[(size_t)(row0 + r) * D_ + tid] = acc[r];
}

extern "C" void kernel_launch(void* const* d_in, const int* in_sizes, int n_in,
                              void* d_out, int out_size, void* d_ws, size_t ws_size,
                              hipStream_t stream) {
  (void)in_sizes; (void)n_in; (void)out_size; (void)ws_size;
  const float* q  = (const float*)d_in[0];
  const float* k  = (const float*)d_in[1];
  const float* v  = (const float*)d_in[2];
  const unsigned char* mask = (const unsigned char*)d_in[3];
  const float* Wq = (const float*)d_in[4];
  const float* bq = (const float*)d_in[5];
  const float* Wk = (const float*)d_in[6];
  const float* bk = (const float*)d_in[7];
  const float* Wv = (const float*)d_in[8];
  const float* bv = (const float*)d_in[9];
  const float* Wf = (const float*)d_in[10];

  float* out  = (float*)d_out;
  float* attn = out + (size_t)B_ * S_ * D_;

  char* ws = (char*)d_ws;
  short* qh    = (short*)(ws);
  short* kh    = (short*)(ws + 4194304);
  short* vT    = (short*)(ws + 8388608);
  short* WqT   = (short*)(ws + 9437184);
  short* WkT   = (short*)(ws + 9568256);
  short* WvT   = (short*)(ws + 9699328);
  float* heads = (float*)(ws + 9732096);
  int*   flag  = (int*)(ws + 18120704);
  uint*  mbits = (uint*)(ws + 18120768);  // 2 MB bit-packed mask

  detect_kernel<<<1, 256, 0, stream>>>((const unsigned int*)mask, flag);
  pack_mask<<<2048, 256, 0, stream>>>(mask, flag, mbits);
  prep_weights<<<320, 256, 0, stream>>>(Wq, Wk, Wv, WqT, WkT, WvT);
  proj_kernel<<<dim3(32, 4, B_), 256, 0, stream>>>(q, WqT, bq, qh, 0);
  proj_kernel<<<dim3(32, 4, B_), 256, 0, stream>>>(k, WkT, bk, kh, 0);
  proj_kernel<<<dim3(32, 1, B_), 256, 0, stream>>>(v, WvT, bv, vT, 1);
  attn_kernel<<<dim3(32, H_, B_), 256, 0, stream>>>(qh, kh, vT, mbits, attn, heads);
  final_kernel<<<512, 256, 0, stream>>>(heads, Wf, out);
}

// Round 6
// 182.701 us; speedup vs baseline: 1.6654x; 1.5290x over previous
//
#include <hip/hip_runtime.h>
#include <stdint.h>
#include <stddef.h>

#define B_ 4
#define S_ 2048
#define D_ 256
#define H_ 4
#define DH_ 64
#define NT 128
#define SC_LOG2E 0.18033688011112042f  // (1/8) * log2(e)

typedef __attribute__((ext_vector_type(8))) short short8;
typedef __attribute__((ext_vector_type(4))) short short4v;
typedef __attribute__((ext_vector_type(4))) float f32x4;
typedef unsigned int uint;

__device__ __forceinline__ short bf16_rne(float f) {
  union { float f; uint32_t u; } c; c.f = f;
  uint32_t u = c.u + 0x7FFFu + ((c.u >> 16) & 1u);
  return (short)(u >> 16);
}

__device__ __forceinline__ f32x4 mfma16(short8 a, short8 b, f32x4 c) {
  return __builtin_amdgcn_mfma_f32_16x16x32_bf16(a, b, c, 0, 0, 0);
}

__device__ __forceinline__ void gl_lds16(const short* g, short* l) {
  __builtin_amdgcn_global_load_lds(
      (const __attribute__((address_space(1))) unsigned int*)g,
      (__attribute__((address_space(3))) unsigned int*)l, 16, 0, 0);
}

// ---------------- weight prep: transpose+cast to bf16 ----------------
__global__ void prep_weights(const float* __restrict__ Wq, const float* __restrict__ Wk,
                             const float* __restrict__ Wv,
                             short* __restrict__ WqT, short* __restrict__ WkT,
                             short* __restrict__ WvT) {
  int tid = blockIdx.x * blockDim.x + threadIdx.x;
  if (tid < 65536) {
    int n = tid >> 8, d = tid & 255;
    int hh = n >> 6, e = n & 63;
    WqT[tid] = bf16_rne(Wq[((size_t)hh * D_ + d) * DH_ + e]);
    WkT[tid] = bf16_rne(Wk[((size_t)hh * D_ + d) * DH_ + e]);
  } else if (tid < 65536 + 16384) {
    int t2 = tid - 65536;
    int e = t2 >> 8, d = t2 & 255;
    WvT[t2] = bf16_rne(Wv[(size_t)d * DH_ + e]);
  }
}

// ---------------- mask dtype detect: 1 = int32, 0 = byte/bool ----------------
__global__ void detect_kernel(const unsigned int* __restrict__ m, int* __restrict__ flag) {
  __shared__ int isbool;
  if (threadIdx.x == 0) isbool = 0;
  __syncthreads();
#pragma unroll
  for (int i = 0; i < 4; ++i) {
    unsigned int d = m[threadIdx.x + i * 256];
    if (d & 0xFFFFFFFEu) isbool = 1;
  }
  __syncthreads();
  if (threadIdx.x == 0) *flag = isbool ? 0 : 1;
}

// ---------------- bit-pack mask: [B,S,S] -> [B,S,S/32] dwords ----------------
__global__ __launch_bounds__(256) void pack_mask(const unsigned char* __restrict__ maskB,
                                                 const int* __restrict__ flagp,
                                                 uint* __restrict__ mbits) {
  int tid = blockIdx.x * 256 + threadIdx.x;  // 524288 dwords total
  uint w = 0;
  if (*flagp) {  // int32 mask
    const uint4* p = (const uint4*)((const uint*)maskB + (size_t)tid * 32);
#pragma unroll
    for (int i = 0; i < 8; ++i) {
      uint4 d = p[i];
      w |= (d.x ? 1u : 0u) << (i * 4);
      w |= (d.y ? 1u : 0u) << (i * 4 + 1);
      w |= (d.z ? 1u : 0u) << (i * 4 + 2);
      w |= (d.w ? 1u : 0u) << (i * 4 + 3);
    }
  } else {  // byte mask
    const uint4* p = (const uint4*)(maskB + (size_t)tid * 32);
#pragma unroll
    for (int i = 0; i < 2; ++i) {
      uint4 d = p[i];
      const uint* dw = (const uint*)&d;
#pragma unroll
      for (int j = 0; j < 4; ++j) {
        uint x = dw[j];
        int base = i * 16 + j * 4;
        w |= ((x & 0x000000FFu) ? 1u : 0u) << (base);
        w |= ((x & 0x0000FF00u) ? 1u : 0u) << (base + 1);
        w |= ((x & 0x00FF0000u) ? 1u : 0u) << (base + 2);
        w |= ((x & 0xFF000000u) ? 1u : 0u) << (base + 3);
      }
    }
  }
  mbits[tid] = w;
}

// ---------------- projections ----------------
__global__ __launch_bounds__(256) void proj_kernel(
    const float* __restrict__ X, const short* __restrict__ WT,
    const float* __restrict__ bias, short* __restrict__ outp, int vmode) {
  const int b = blockIdx.z;
  const int s0 = blockIdx.x * 64;
  const int n0 = blockIdx.y * 64;
  const int tid = threadIdx.x;
  const int wave = tid >> 6, lane = tid & 63;
  const int lr = lane & 15, lg = lane >> 4;

  const int arowi = s0 + wave * 16 + lr;
  const float* xr = X + ((size_t)b * S_ + arowi) * D_;

  f32x4 zero4 = {0.f, 0.f, 0.f, 0.f};
  f32x4 acc[4];
#pragma unroll
  for (int ct = 0; ct < 4; ++ct) acc[ct] = zero4;

#pragma unroll
  for (int c = 0; c < 8; ++c) {
    const int k0 = c * 32 + lg * 8;
    f32x4 x0 = *(const f32x4*)(xr + k0);
    f32x4 x1 = *(const f32x4*)(xr + k0 + 4);
    short8 a;
#pragma unroll
    for (int jj = 0; jj < 4; ++jj) { a[jj] = bf16_rne(x0[jj]); a[4 + jj] = bf16_rne(x1[jj]); }
#pragma unroll
    for (int ct = 0; ct < 4; ++ct) {
      short8 bw = *(const short8*)(WT + (size_t)(n0 + ct * 16 + lr) * D_ + k0);
      acc[ct] = mfma16(a, bw, acc[ct]);
    }
  }

  if (vmode == 0) {
#pragma unroll
    for (int ct = 0; ct < 4; ++ct) {
      int n = n0 + ct * 16 + lr;
      float bb = bias[n];
      int hh = n >> 6, e = n & 63;
#pragma unroll
      for (int r = 0; r < 4; ++r) {
        int srow = s0 + wave * 16 + lg * 4 + r;
        outp[(((size_t)b * H_ + hh) * S_ + srow) * DH_ + e] = bf16_rne(acc[ct][r] + bb);
      }
    }
  } else {
#pragma unroll
    for (int ct = 0; ct < 4; ++ct) {
      int n = n0 + ct * 16 + lr;
      float bb = bias[n];
      int s4 = s0 + wave * 16 + lg * 4;
      short4v pk;
#pragma unroll
      for (int r = 0; r < 4; ++r) pk[r] = bf16_rne(acc[ct][r] + bb);
      *(short4v*)(outp + ((size_t)b * DH_ + n) * S_ + s4) = pk;
    }
  }
}

// ---------------- staging helpers (inverse-swizzled global source) ----------------
__device__ __forceinline__ void stageK(const short* Ksrc, short* dst, int wave, int lane) {
#pragma unroll
  for (int i = 0; i < 4; ++i) {
    int db = i * 256 + wave * 64;
    int d = db + lane;
    int s = (d & ~7) | ((d ^ (d >> 3)) & 7);
    gl_lds16(Ksrc + (size_t)s * 8, dst + (size_t)db * 8);
  }
}

__device__ __forceinline__ void stageV(const short* Vb, int t0, short* dst, int wave, int lane) {
#pragma unroll
  for (int i = 0; i < 4; ++i) {
    int db = i * 256 + wave * 64;
    int d = db + lane;
    int s = (d & ~15) | ((d ^ (d >> 4)) & 15);
    int er = s >> 4, c16 = s & 15;
    gl_lds16(Vb + (size_t)er * S_ + t0 + c16 * 8, dst + (size_t)db * 8);
  }
}

// ---------------- fused masked attention (R2 structure + XCD swizzle) ----------------
// grid 512 (1D), 256 thr. Decode: xcd = flat&7, bh = xcd*2 + (pos>>5), q0 = (pos&31)*64.
// All 32 q-blocks of one (b,h) land on ONE XCD -> K/V (512 KB x 2 bh) stay in its 4 MB L2.
// Swapped-MFMA lane layout: q = lr, t = lg*4+r. LDS-staged K/V (gl_lds, dbuf, swizzled).
__global__ __launch_bounds__(256) void attn_kernel(
    const short* __restrict__ qh, const short* __restrict__ kh,
    const short* __restrict__ vT, const uint* __restrict__ mbits,
    float* __restrict__ attn, float* __restrict__ heads) {
  __shared__ __align__(16) short Kt[2][NT][DH_];   // 32 KB (dbuf, swizzled)
  __shared__ __align__(16) short Vt[2][DH_][NT];   // 32 KB (dbuf, swizzled)
  __shared__ __align__(16) short Pt[4][16][NT];    // 16 KB (per-wave, swizzled)

  const int flat = blockIdx.x;
  const int xcd = flat & 7;
  const int pos = flat >> 3;            // 0..63
  const int bh_i = xcd * 2 + (pos >> 5);  // 2 (b,h) per XCD
  const int q0 = (pos & 31) * 64;
  const int b = bh_i >> 2, h = bh_i & 3;

  const int tid = threadIdx.x;
  const int wave = tid >> 6, lane = tid & 63;
  const int lr = lane & 15, lg = lane >> 4;

  const size_t bh = (size_t)b * H_ + h;
  const short* Qb = qh + bh * S_ * DH_;
  const short* Kb = kh + bh * S_ * DH_;
  const short* Vb = vT + (size_t)b * DH_ * S_;

  const int qrow = q0 + wave * 16 + lr;
  const uint* mrow = mbits + ((size_t)b * S_ + qrow) * (S_ / 32);
  float* arow = attn + (bh * S_ + qrow) * S_;

  short8 aq0 = *(const short8*)(Qb + (size_t)qrow * DH_ + lg * 8);
  short8 aq1 = *(const short8*)(Qb + (size_t)qrow * DH_ + 32 + lg * 8);

  short* pw = &Pt[wave][0][0];

  // -------- pass 1: row sums (K double-buffered) --------
  float rsum = 0.f;
  stageK(Kb, &Kt[0][0][0], wave, lane);
  __syncthreads();
  int cur = 0;
  for (int t0 = 0; t0 < S_; t0 += NT) {
    if (t0 + NT < S_) stageK(Kb + (size_t)(t0 + NT) * DH_, &Kt[cur ^ 1][0][0], wave, lane);
    const short* kt = &Kt[cur][0][0];
    uint4 mv = *(const uint4*)(mrow + (t0 >> 5));
#pragma unroll
    for (int j = 0; j < 8; ++j) {
      int row = j * 16 + lr;
      int rs = row & 7;
      short8 bk0 = *(const short8*)(kt + row * 64 + ((lg ^ rs) * 8));
      short8 bk1 = *(const short8*)(kt + row * 64 + (((lg + 4) ^ rs) * 8));
      f32x4 acc = {0.f, 0.f, 0.f, 0.f};
      acc = mfma16(bk0, aq0, acc);
      acc = mfma16(bk1, aq1, acc);
      uint mw = ((const uint*)&mv)[j >> 1];
#pragma unroll
      for (int r = 0; r < 4; ++r) {
        int sh = (j & 1) * 16 + lg * 4 + r;
        float p = ((mw >> sh) & 1u) ? 0.f : __builtin_exp2f(acc[r] * SC_LOG2E);
        rsum += p;
      }
    }
    __syncthreads();
    cur ^= 1;
  }
  rsum += __shfl_xor(rsum, 16);
  rsum += __shfl_xor(rsum, 32);
  const float rinv = 1.0f / rsum;

  // -------- pass 2: recompute, write attn (float4), PV --------
  f32x4 o[4];
#pragma unroll
  for (int ct = 0; ct < 4; ++ct) o[ct] = (f32x4){0.f, 0.f, 0.f, 0.f};

  stageK(Kb, &Kt[0][0][0], wave, lane);
  stageV(Vb, 0, &Vt[0][0][0], wave, lane);
  __syncthreads();
  cur = 0;
  for (int t0 = 0; t0 < S_; t0 += NT) {
    if (t0 + NT < S_) {
      stageK(Kb + (size_t)(t0 + NT) * DH_, &Kt[cur ^ 1][0][0], wave, lane);
      stageV(Vb, t0 + NT, &Vt[cur ^ 1][0][0], wave, lane);
    }
    const short* kt = &Kt[cur][0][0];
    const short* vt = &Vt[cur][0][0];
    uint4 mv = *(const uint4*)(mrow + (t0 >> 5));
#pragma unroll
    for (int j = 0; j < 8; ++j) {
      int row = j * 16 + lr;
      int rs = row & 7;
      short8 bk0 = *(const short8*)(kt + row * 64 + ((lg ^ rs) * 8));
      short8 bk1 = *(const short8*)(kt + row * 64 + (((lg + 4) ^ rs) * 8));
      f32x4 acc = {0.f, 0.f, 0.f, 0.f};
      acc = mfma16(bk0, aq0, acc);
      acc = mfma16(bk1, aq1, acc);
      uint mw = ((const uint*)&mv)[j >> 1];
      f32x4 pst;
      short4v pk;
#pragma unroll
      for (int r = 0; r < 4; ++r) {
        int sh = (j & 1) * 16 + lg * 4 + r;
        float p = ((mw >> sh) & 1u) ? 0.f : __builtin_exp2f(acc[r] * SC_LOG2E) * rinv;
        pst[r] = p;
        pk[r] = bf16_rne(p);
      }
      *(f32x4*)(arow + t0 + j * 16 + lg * 4) = pst;
      int slot = j * 2 + (lg >> 1);
      *(short4v*)(pw + lr * 128 + ((slot ^ lr) * 8) + (lg & 1) * 4) = pk;
    }
    // PV: o[e][q] += V^T[e][t] * P[q][t]
#pragma unroll
    for (int ct = 0; ct < 4; ++ct) {
#pragma unroll
      for (int kc = 0; kc < 4; ++kc) {
        short8 apf = *(const short8*)(pw + lr * 128 + (((kc * 4 + lg) ^ lr) * 8));
        int er = ct * 16 + lr;
        short8 bvf = *(const short8*)(vt + er * 128 + (((kc * 4 + lg) ^ (er & 15)) * 8));
        o[ct] = mfma16(bvf, apf, o[ct]);
      }
    }
    __syncthreads();
    cur ^= 1;
  }

#pragma unroll
  for (int ct = 0; ct < 4; ++ct)
    *(f32x4*)(heads + (bh * S_ + qrow) * DH_ + ct * 16 + lg * 4) = o[ct];
}

// ---------------- mean over heads + final projection ----------------
__global__ __launch_bounds__(256) void final_kernel(
    const float* __restrict__ heads, const float* __restrict__ Wf,
    float* __restrict__ outp) {
  __shared__ float mean[16][DH_];
  const int row0 = blockIdx.x * 16;
  const int tid = threadIdx.x;
#pragma unroll
  for (int i = 0; i < 4; ++i) {
    int idx = tid + i * 256;
    int r = idx >> 6, e = idx & 63;
    int gs = row0 + r;
    int bb = gs >> 11, ss = gs & (S_ - 1);
    float acc = 0.f;
#pragma unroll
    for (int hh = 0; hh < H_; ++hh)
      acc += heads[(((size_t)bb * H_ + hh) * S_ + ss) * DH_ + e];
    mean[r][e] = acc * 0.25f;
  }
  __syncthreads();
  float acc[16];
#pragma unroll
  for (int r = 0; r < 16; ++r) acc[r] = 0.f;
  for (int e = 0; e < DH_; ++e) {
    float wf = Wf[(size_t)e * D_ + tid];
#pragma unroll
    for (int r = 0; r < 16; ++r) acc[r] += mean[r][e] * wf;
  }
#pragma unroll
  for (int r = 0; r < 16; ++r)
    outp[(size_t)(row0 + r) * D_ + tid] = acc[r];
}

extern "C" void kernel_launch(void* const* d_in, const int* in_sizes, int n_in,
                              void* d_out, int out_size, void* d_ws, size_t ws_size,
                              hipStream_t stream) {
  (void)in_sizes; (void)n_in; (void)out_size; (void)ws_size;
  const float* q  = (const float*)d_in[0];
  const float* k  = (const float*)d_in[1];
  const float* v  = (const float*)d_in[2];
  const unsigned char* mask = (const unsigned char*)d_in[3];
  const float* Wq = (const float*)d_in[4];
  const float* bq = (const float*)d_in[5];
  const float* Wk = (const float*)d_in[6];
  const float* bk = (const float*)d_in[7];
  const float* Wv = (const float*)d_in[8];
  const float* bv = (const float*)d_in[9];
  const float* Wf = (const float*)d_in[10];

  float* out  = (float*)d_out;
  float* attn = out + (size_t)B_ * S_ * D_;

  char* ws = (char*)d_ws;
  short* qh    = (short*)(ws);
  short* kh    = (short*)(ws + 4194304);
  short* vT    = (short*)(ws + 8388608);
  short* WqT   = (short*)(ws + 9437184);
  short* WkT   = (short*)(ws + 9568256);
  short* WvT   = (short*)(ws + 9699328);
  float* heads = (float*)(ws + 9732096);
  int*   flag  = (int*)(ws + 18120704);
  uint*  mbits = (uint*)(ws + 18120768);  // 2 MB bit-packed mask

  detect_kernel<<<1, 256, 0, stream>>>((const unsigned int*)mask, flag);
  pack_mask<<<2048, 256, 0, stream>>>(mask, flag, mbits);
  prep_weights<<<320, 256, 0, stream>>>(Wq, Wk, Wv, WqT, WkT, WvT);
  proj_kernel<<<dim3(32, 4, B_), 256, 0, stream>>>(q, WqT, bq, qh, 0);
  proj_kernel<<<dim3(32, 4, B_), 256, 0, stream>>>(k, WkT, bk, kh, 0);
  proj_kernel<<<dim3(32, 1, B_), 256, 0, stream>>>(v, WvT, bv, vT, 1);
  attn_kernel<<<512, 256, 0, stream>>>(qh, kh, vT, mbits, attn, heads);
  final_kernel<<<512, 256, 0, stream>>>(heads, Wf, out);
}

// Round 7
// 172.069 us; speedup vs baseline: 1.7683x; 1.0618x over previous
//
#include <hip/hip_runtime.h>
#include <stdint.h>
#include <stddef.h>

#define B_ 4
#define S_ 2048
#define D_ 256
#define H_ 4
#define DH_ 64
#define NTT 64
#define SC_LOG2E 0.18033688011112042f  // (1/8) * log2(e)

typedef __attribute__((ext_vector_type(8))) short short8;
typedef __attribute__((ext_vector_type(4))) short short4v;
typedef __attribute__((ext_vector_type(4))) float f32x4;
typedef unsigned int uint;

__device__ __forceinline__ short bf16_rne(float f) {
  union { float f; uint32_t u; } c; c.f = f;
  uint32_t u = c.u + 0x7FFFu + ((c.u >> 16) & 1u);
  return (short)(u >> 16);
}

__device__ __forceinline__ f32x4 mfma16(short8 a, short8 b, f32x4 c) {
  return __builtin_amdgcn_mfma_f32_16x16x32_bf16(a, b, c, 0, 0, 0);
}

__device__ __forceinline__ void gl_lds16(const short* g, short* l) {
  __builtin_amdgcn_global_load_lds(
      (const __attribute__((address_space(1))) unsigned int*)g,
      (__attribute__((address_space(3))) unsigned int*)l, 16, 0, 0);
}

// ---------------- weight prep: transpose+cast to bf16 (Wq pre-scaled) ----------------
__global__ void prep_weights(const float* __restrict__ Wq, const float* __restrict__ Wk,
                             const float* __restrict__ Wv,
                             short* __restrict__ WqT, short* __restrict__ WkT,
                             short* __restrict__ WvT) {
  int tid = blockIdx.x * blockDim.x + threadIdx.x;
  if (tid < 65536) {
    int n = tid >> 8, d = tid & 255;
    int hh = n >> 6, e = n & 63;
    WqT[tid] = bf16_rne(Wq[((size_t)hh * D_ + d) * DH_ + e] * SC_LOG2E);
    WkT[tid] = bf16_rne(Wk[((size_t)hh * D_ + d) * DH_ + e]);
  } else if (tid < 65536 + 16384) {
    int t2 = tid - 65536;
    int e = t2 >> 8, d = t2 & 255;
    WvT[t2] = bf16_rne(Wv[(size_t)d * DH_ + e]);
  }
}

// ---------------- mask dtype detect: 1 = int32, 0 = byte/bool ----------------
__global__ void detect_kernel(const unsigned int* __restrict__ m, int* __restrict__ flag) {
  __shared__ int isbool;
  if (threadIdx.x == 0) isbool = 0;
  __syncthreads();
#pragma unroll
  for (int i = 0; i < 4; ++i) {
    unsigned int d = m[threadIdx.x + i * 256];
    if (d & 0xFFFFFFFEu) isbool = 1;
  }
  __syncthreads();
  if (threadIdx.x == 0) *flag = isbool ? 0 : 1;
}

// ---------------- bit-pack mask: [B,S,S] -> [B,S,S/32] dwords ----------------
__global__ __launch_bounds__(256) void pack_mask(const unsigned char* __restrict__ maskB,
                                                 const int* __restrict__ flagp,
                                                 uint* __restrict__ mbits) {
  int tid = blockIdx.x * 256 + threadIdx.x;  // 524288 dwords total
  uint w = 0;
  if (*flagp) {  // int32 mask
    const uint4* p = (const uint4*)((const uint*)maskB + (size_t)tid * 32);
#pragma unroll
    for (int i = 0; i < 8; ++i) {
      uint4 d = p[i];
      w |= (d.x ? 1u : 0u) << (i * 4);
      w |= (d.y ? 1u : 0u) << (i * 4 + 1);
      w |= (d.z ? 1u : 0u) << (i * 4 + 2);
      w |= (d.w ? 1u : 0u) << (i * 4 + 3);
    }
  } else {  // byte mask
    const uint4* p = (const uint4*)(maskB + (size_t)tid * 32);
#pragma unroll
    for (int i = 0; i < 2; ++i) {
      uint4 d = p[i];
      const uint* dw = (const uint*)&d;
#pragma unroll
      for (int j = 0; j < 4; ++j) {
        uint x = dw[j];
        int base = i * 16 + j * 4;
        w |= ((x & 0x000000FFu) ? 1u : 0u) << (base);
        w |= ((x & 0x0000FF00u) ? 1u : 0u) << (base + 1);
        w |= ((x & 0x00FF0000u) ? 1u : 0u) << (base + 2);
        w |= ((x & 0xFF000000u) ? 1u : 0u) << (base + 3);
      }
    }
  }
  mbits[tid] = w;
}

// ---------------- projections ----------------
__global__ __launch_bounds__(256) void proj_kernel(
    const float* __restrict__ X, const short* __restrict__ WT,
    const float* __restrict__ bias, short* __restrict__ outp, int vmode, float bscale) {
  const int b = blockIdx.z;
  const int s0 = blockIdx.x * 64;
  const int n0 = blockIdx.y * 64;
  const int tid = threadIdx.x;
  const int wave = tid >> 6, lane = tid & 63;
  const int lr = lane & 15, lg = lane >> 4;

  const int arowi = s0 + wave * 16 + lr;
  const float* xr = X + ((size_t)b * S_ + arowi) * D_;

  f32x4 zero4 = {0.f, 0.f, 0.f, 0.f};
  f32x4 acc[4];
#pragma unroll
  for (int ct = 0; ct < 4; ++ct) acc[ct] = zero4;

#pragma unroll
  for (int c = 0; c < 8; ++c) {
    const int k0 = c * 32 + lg * 8;
    f32x4 x0 = *(const f32x4*)(xr + k0);
    f32x4 x1 = *(const f32x4*)(xr + k0 + 4);
    short8 a;
#pragma unroll
    for (int jj = 0; jj < 4; ++jj) { a[jj] = bf16_rne(x0[jj]); a[4 + jj] = bf16_rne(x1[jj]); }
#pragma unroll
    for (int ct = 0; ct < 4; ++ct) {
      short8 bw = *(const short8*)(WT + (size_t)(n0 + ct * 16 + lr) * D_ + k0);
      acc[ct] = mfma16(a, bw, acc[ct]);
    }
  }

  if (vmode == 0) {
#pragma unroll
    for (int ct = 0; ct < 4; ++ct) {
      int n = n0 + ct * 16 + lr;
      float bb = bias[n] * bscale;
      int hh = n >> 6, e = n & 63;
#pragma unroll
      for (int r = 0; r < 4; ++r) {
        int srow = s0 + wave * 16 + lg * 4 + r;
        outp[(((size_t)b * H_ + hh) * S_ + srow) * DH_ + e] = bf16_rne(acc[ct][r] + bb);
      }
    }
  } else {
#pragma unroll
    for (int ct = 0; ct < 4; ++ct) {
      int n = n0 + ct * 16 + lr;
      float bb = bias[n];
      int s4 = s0 + wave * 16 + lg * 4;
      short4v pk;
#pragma unroll
      for (int r = 0; r < 4; ++r) pk[r] = bf16_rne(acc[ct][r] + bb);
      *(short4v*)(outp + ((size_t)b * DH_ + n) * S_ + s4) = pk;
    }
  }
}

// ---------------- staging helpers (NTT=64 tiles, inverse-swizzled source) ----------------
// Tile = 512 16B-units; 4 waves x 2 rounds x 64 lanes cover it. LDS dst linear (uniform base).
__device__ __forceinline__ void stageK64(const short* Ksrc, short* dst, int wq, int lane) {
#pragma unroll
  for (int i = 0; i < 2; ++i) {
    int ub = i * 256 + wq * 64;
    int u = ub + lane;
    int row = u >> 3, c = (u ^ row) & 7;
    gl_lds16(Ksrc + (size_t)row * 64 + c * 8, dst + (size_t)ub * 8);
  }
}

__device__ __forceinline__ void stageV64(const short* Vb, int t0, short* dst, int wq, int lane) {
#pragma unroll
  for (int i = 0; i < 2; ++i) {
    int ub = i * 256 + wq * 64;
    int u = ub + lane;
    int er = u >> 3, c = (u ^ er) & 7;
    gl_lds16(Vb + (size_t)er * S_ + t0 + c * 8, dst + (size_t)ub * 8);
  }
}

// ---------------- fused masked attention (t-split x2, 8 waves, 16 waves/CU) ----------------
// grid 512 (XCD-swizzled), 512 thr. Waves 0-3: t in [0,1024); waves 4-7: t in [1024,2048).
// Wave (half, wq) owns q-rows [q0+wq*16, +16) over its t-half. K/V LDS-staged per half
// (gl_lds, dbuf, XOR-swizzled). Lane layout (swapped MFMA): q = lr, t = lg*4+r.
__global__ __launch_bounds__(512, 4) void attn_kernel(
    const short* __restrict__ qh, const short* __restrict__ kh,
    const short* __restrict__ vT, const uint* __restrict__ mbits,
    float* __restrict__ attn, float* __restrict__ heads) {
  __shared__ __align__(16) short Kt[2][2][4096];  // [half][dbuf] 32 KB
  __shared__ __align__(16) short Vt[2][2][4096];  // [half][dbuf] 32 KB
  __shared__ __align__(16) short Pt[8][1024];     // per-wave P slab, 16 KB (aliased: fsum, ocomb)

  const int flat = blockIdx.x;
  const int xcd = flat & 7;
  const int pos = flat >> 3;              // 0..63
  const int bh_i = xcd * 2 + (pos >> 5);  // 2 (b,h) per XCD (same b -> shared V in L2)
  const int q0 = (pos & 31) * 64;
  const int b = bh_i >> 2, h = bh_i & 3;

  const int tid = threadIdx.x;
  const int wave = tid >> 6, lane = tid & 63;
  const int half = wave >> 2, wq = wave & 3;
  const int lr = lane & 15, lg = lane >> 4;
  const int tbase = half * (S_ / 2);

  const size_t bh = (size_t)b * H_ + h;
  const short* Qb = qh + bh * S_ * DH_;
  const short* Kb = kh + bh * S_ * DH_;
  const short* Vb = vT + (size_t)b * DH_ * S_;

  const int qrow = q0 + wq * 16 + lr;
  const uint* mrow = mbits + ((size_t)b * S_ + qrow) * (S_ / 32);
  float* arow = attn + (bh * S_ + qrow) * S_;

  const short8 aq0 = *(const short8*)(Qb + (size_t)qrow * DH_ + lg * 8);
  const short8 aq1 = *(const short8*)(Qb + (size_t)qrow * DH_ + 32 + lg * 8);

  short* pw = &Pt[wave][0];

  // -------- pass 1: partial row sums over this wave's t-half --------
  float rsum = 0.f;
  stageK64(Kb + (size_t)tbase * DH_, Kt[half][0], wq, lane);
  __syncthreads();
  int cur = 0;
  for (int tt = 0; tt < 16; ++tt) {
    const int t0 = tbase + tt * NTT;
    if (tt + 1 < 16) stageK64(Kb + (size_t)(t0 + NTT) * DH_, Kt[half][cur ^ 1], wq, lane);
    const short* kt = Kt[half][cur];
    uint2 mv = *(const uint2*)(mrow + (t0 >> 5));
#pragma unroll
    for (int j = 0; j < 4; ++j) {
      int row = j * 16 + lr;
      short8 bk0 = *(const short8*)(kt + row * 64 + (((lg) ^ row) & 7) * 8);
      short8 bk1 = *(const short8*)(kt + row * 64 + (((lg + 4) ^ row) & 7) * 8);
      f32x4 acc = {0.f, 0.f, 0.f, 0.f};
      acc = mfma16(bk0, aq0, acc);
      acc = mfma16(bk1, aq1, acc);
      uint mw = (j < 2) ? mv.x : mv.y;
#pragma unroll
      for (int r = 0; r < 4; ++r) {
        int sh = (j & 1) * 16 + lg * 4 + r;
        float p = ((mw >> sh) & 1u) ? 0.f : __builtin_exp2f(acc[r]);
        rsum += p;
      }
    }
    __syncthreads();
    cur ^= 1;
  }
  rsum += __shfl_xor(rsum, 16);
  rsum += __shfl_xor(rsum, 32);
  // combine the two t-halves through LDS (fsum aliased onto Pt)
  float* fsum = (float*)&Pt[0][0];  // [8][16]
  if (lane < 16) fsum[wave * 16 + lr] = rsum;
  __syncthreads();
  const float rinv = 1.0f / (fsum[wq * 16 + lr] + fsum[(wq + 4) * 16 + lr]);

  // -------- pass 2: recompute, write attn (float4), PV partials --------
  f32x4 o[4];
#pragma unroll
  for (int ct = 0; ct < 4; ++ct) o[ct] = (f32x4){0.f, 0.f, 0.f, 0.f};

  stageK64(Kb + (size_t)tbase * DH_, Kt[half][0], wq, lane);
  stageV64(Vb, tbase, Vt[half][0], wq, lane);
  __syncthreads();
  cur = 0;
  for (int tt = 0; tt < 16; ++tt) {
    const int t0 = tbase + tt * NTT;
    if (tt + 1 < 16) {
      stageK64(Kb + (size_t)(t0 + NTT) * DH_, Kt[half][cur ^ 1], wq, lane);
      stageV64(Vb, t0 + NTT, Vt[half][cur ^ 1], wq, lane);
    }
    const short* kt = Kt[half][cur];
    const short* vt = Vt[half][cur];
    uint2 mv = *(const uint2*)(mrow + (t0 >> 5));
#pragma unroll
    for (int j = 0; j < 4; ++j) {
      int row = j * 16 + lr;
      short8 bk0 = *(const short8*)(kt + row * 64 + (((lg) ^ row) & 7) * 8);
      short8 bk1 = *(const short8*)(kt + row * 64 + (((lg + 4) ^ row) & 7) * 8);
      f32x4 acc = {0.f, 0.f, 0.f, 0.f};
      acc = mfma16(bk0, aq0, acc);
      acc = mfma16(bk1, aq1, acc);
      uint mw = (j < 2) ? mv.x : mv.y;
      f32x4 pst;
      short4v pk;
#pragma unroll
      for (int r = 0; r < 4; ++r) {
        int sh = (j & 1) * 16 + lg * 4 + r;
        float p = ((mw >> sh) & 1u) ? 0.f : __builtin_exp2f(acc[r]) * rinv;
        pst[r] = p;
        pk[r] = bf16_rne(p);
      }
      *(f32x4*)(arow + t0 + j * 16 + lg * 4) = pst;
      *(short4v*)(pw + lr * 64 + (((2 * j + (lg >> 1)) ^ lr) & 7) * 8 + (lg & 1) * 4) = pk;
    }
    // PV: o[e][q] += V^T[e][t] * P[q][t]; apf is ct-invariant -> hoisted
    short8 apf[2];
#pragma unroll
    for (int kc = 0; kc < 2; ++kc)
      apf[kc] = *(const short8*)(pw + lr * 64 + (((4 * kc + lg) ^ lr) & 7) * 8);
#pragma unroll
    for (int ct = 0; ct < 4; ++ct) {
      int er = ct * 16 + lr;
#pragma unroll
      for (int kc = 0; kc < 2; ++kc) {
        short8 bvf = *(const short8*)(vt + er * 64 + (((4 * kc + lg) ^ er) & 7) * 8);
        o[ct] = mfma16(bvf, apf[kc], o[ct]);
      }
    }
    __syncthreads();
    cur ^= 1;
  }

  // -------- combine o partials across the two t-halves (ocomb aliased onto Pt) --------
  float* ocomb = (float*)&Pt[0][0];  // [4][16][64] floats = 16 KB
  if (half == 1) {
#pragma unroll
    for (int ct = 0; ct < 4; ++ct)
      *(f32x4*)(ocomb + wq * 1024 + lr * 64 + ct * 16 + lg * 4) = o[ct];
  }
  __syncthreads();
  if (half == 0) {
#pragma unroll
    for (int ct = 0; ct < 4; ++ct) {
      f32x4 t = *(const f32x4*)(ocomb + wq * 1024 + lr * 64 + ct * 16 + lg * 4);
      f32x4 s = o[ct];
      s[0] += t[0]; s[1] += t[1]; s[2] += t[2]; s[3] += t[3];
      *(f32x4*)(heads + (bh * S_ + qrow) * DH_ + ct * 16 + lg * 4) = s;
    }
  }
}

// ---------------- mean over heads + final projection ----------------
__global__ __launch_bounds__(256) void final_kernel(
    const float* __restrict__ heads, const float* __restrict__ Wf,
    float* __restrict__ outp) {
  __shared__ float mean[16][DH_];
  const int row0 = blockIdx.x * 16;
  const int tid = threadIdx.x;
#pragma unroll
  for (int i = 0; i < 4; ++i) {
    int idx = tid + i * 256;
    int r = idx >> 6, e = idx & 63;
    int gs = row0 + r;
    int bb = gs >> 11, ss = gs & (S_ - 1);
    float acc = 0.f;
#pragma unroll
    for (int hh = 0; hh < H_; ++hh)
      acc += heads[(((size_t)bb * H_ + hh) * S_ + ss) * DH_ + e];
    mean[r][e] = acc * 0.25f;
  }
  __syncthreads();
  float acc[16];
#pragma unroll
  for (int r = 0; r < 16; ++r) acc[r] = 0.f;
  for (int e = 0; e < DH_; ++e) {
    float wf = Wf[(size_t)e * D_ + tid];
#pragma unroll
    for (int r = 0; r < 16; ++r) acc[r] += mean[r][e] * wf;
  }
#pragma unroll
  for (int r = 0; r < 16; ++r)
    outp[(size_t)(row0 + r) * D_ + tid] = acc[r];
}

extern "C" void kernel_launch(void* const* d_in, const int* in_sizes, int n_in,
                              void* d_out, int out_size, void* d_ws, size_t ws_size,
                              hipStream_t stream) {
  (void)in_sizes; (void)n_in; (void)out_size; (void)ws_size;
  const float* q  = (const float*)d_in[0];
  const float* k  = (const float*)d_in[1];
  const float* v  = (const float*)d_in[2];
  const unsigned char* mask = (const unsigned char*)d_in[3];
  const float* Wq = (const float*)d_in[4];
  const float* bq = (const float*)d_in[5];
  const float* Wk = (const float*)d_in[6];
  const float* bk = (const float*)d_in[7];
  const float* Wv = (const float*)d_in[8];
  const float* bv = (const float*)d_in[9];
  const float* Wf = (const float*)d_in[10];

  float* out  = (float*)d_out;
  float* attn = out + (size_t)B_ * S_ * D_;

  char* ws = (char*)d_ws;
  short* qh    = (short*)(ws);
  short* kh    = (short*)(ws + 4194304);
  short* vT    = (short*)(ws + 8388608);
  short* WqT   = (short*)(ws + 9437184);
  short* WkT   = (short*)(ws + 9568256);
  short* WvT   = (short*)(ws + 9699328);
  float* heads = (float*)(ws + 9732096);
  int*   flag  = (int*)(ws + 18120704);
  uint*  mbits = (uint*)(ws + 18120768);  // 2 MB bit-packed mask

  detect_kernel<<<1, 256, 0, stream>>>((const unsigned int*)mask, flag);
  pack_mask<<<2048, 256, 0, stream>>>(mask, flag, mbits);
  prep_weights<<<320, 256, 0, stream>>>(Wq, Wk, Wv, WqT, WkT, WvT);
  proj_kernel<<<dim3(32, 4, B_), 256, 0, stream>>>(q, WqT, bq, qh, 0, SC_LOG2E);
  proj_kernel<<<dim3(32, 4, B_), 256, 0, stream>>>(k, WkT, bk, kh, 0, 1.0f);
  proj_kernel<<<dim3(32, 1, B_), 256, 0, stream>>>(v, WvT, bv, vT, 1, 1.0f);
  attn_kernel<<<512, 512, 0, stream>>>(qh, kh, vT, mbits, attn, heads);
  final_kernel<<<512, 256, 0, stream>>>(heads, Wf, out);
}